// Round 1
// baseline (461.828 us; speedup 1.0000x reference)
//
#include <hip/hip_runtime.h>
#include <cstdint>

#define NNODES 8192
#define NEDGES 262144
#define NRELS  8
#define EMBD   256
#define BOXD   1024
#define HIDD   512
#define OUTD   256
#define NSEG   (NRELS * NNODES)      // 65536
#define K0DIM  (BOXD + EMBD)         // 1280
#define KSDIM  (NRELS * HIDD + HIDD) // 4608

using bf16x8 = __attribute__((ext_vector_type(8))) short;
using f32x4  = __attribute__((ext_vector_type(4))) float;

__device__ __forceinline__ unsigned short f2b(float f) {
    union { float f; uint32_t u; } v; v.f = f;
    uint32_t r = v.u + 0x7FFFu + ((v.u >> 16) & 1u);
    return (unsigned short)(r >> 16);
}

// ---------------------------------------------------------------------------
// Build X0 bf16 [8192][1280] = concat(box, emb[labels])
// ---------------------------------------------------------------------------
__global__ void k_build_x0(const float* __restrict__ box, const int* __restrict__ labels,
                           const float* __restrict__ emb, unsigned short* __restrict__ X0) {
    int n = blockIdx.x;
    int lab = labels[n];
    const float* b = box + (size_t)n * BOXD;
    const float* e = emb + (size_t)lab * EMBD;
    unsigned short* o = X0 + (size_t)n * K0DIM;
    for (int j = threadIdx.x; j < BOXD; j += 256) o[j] = f2b(b[j]);
    for (int j = threadIdx.x; j < EMBD; j += 256) o[BOXD + j] = f2b(e[j]);
}

// ---------------------------------------------------------------------------
// Tiled transpose fp32 [Ks][No] -> bf16 dst[o][kOff + k], row stride ldDst
// ---------------------------------------------------------------------------
__global__ void k_transpose(const float* __restrict__ src, unsigned short* __restrict__ dst,
                            int No, int ldDst, int kOff) {
    __shared__ float t[32][33];
    int kt = blockIdx.x * 32, ot = blockIdx.y * 32;
    int tx = threadIdx.x & 31, ty = threadIdx.x >> 5; // 32 x 8
#pragma unroll
    for (int i = 0; i < 4; i++) {
        int k = kt + ty + i * 8;
        t[ty + i * 8][tx] = src[(size_t)k * No + ot + tx];
    }
    __syncthreads();
#pragma unroll
    for (int i = 0; i < 4; i++) {
        int o = ot + ty + i * 8;
        dst[(size_t)o * ldDst + kOff + kt + tx] = f2b(t[tx][ty + i * 8]);
    }
}

// ---------------------------------------------------------------------------
// CSR build
// ---------------------------------------------------------------------------
__global__ void k_hist(const int* __restrict__ etype, const int* __restrict__ edst,
                       int* __restrict__ cnt) {
    int e = blockIdx.x * 256 + threadIdx.x;
    if (e >= NEDGES) return;
    atomicAdd(&cnt[etype[e] * NNODES + edst[e]], 1);
}

__global__ void k_scan(const int* __restrict__ cnt, int* __restrict__ segstart) {
    __shared__ int part[256];
    __shared__ int pre[257];
    int t = threadIdx.x;
    int base = t * 256;
    int s = 0;
    for (int i = 0; i < 256; i++) s += cnt[base + i];
    part[t] = s;
    __syncthreads();
    if (t == 0) {
        int a = 0;
        for (int i = 0; i < 256; i++) { pre[i] = a; a += part[i]; }
        pre[256] = a;
    }
    __syncthreads();
    int a = pre[t];
    for (int i = 0; i < 256; i++) { segstart[base + i] = a; a += cnt[base + i]; }
    if (t == 255) segstart[NSEG] = a;
}

__global__ void k_scatter(const int* __restrict__ etype, const int* __restrict__ esrc,
                          const int* __restrict__ edst, const int* __restrict__ segstart,
                          int* __restrict__ cursor, int* __restrict__ esorted) {
    int e = blockIdx.x * 256 + threadIdx.x;
    if (e >= NEDGES) return;
    int key = etype[e] * NNODES + edst[e];
    int pos = atomicAdd(&cursor[key], 1);
    esorted[segstart[key] + pos] = esrc[e];
}

__global__ void k_inv(const int* __restrict__ cnt, float* __restrict__ inv) {
    int s = blockIdx.x * 256 + threadIdx.x;
    if (s >= NSEG) return;
    int c = cnt[s];
    inv[s] = 1.0f / (float)(c > 0 ? c : 1);
}

// ---------------------------------------------------------------------------
// Aggregation: one wave per (rel,dst) segment.
// Xin[dst][r*512 + j] = bf16( mean over edges of x[src][j] )
// ---------------------------------------------------------------------------
__global__ __launch_bounds__(256) void k_aggregate(
        const float* __restrict__ x, const int* __restrict__ segstart,
        const int* __restrict__ esorted, const float* __restrict__ inv,
        unsigned short* __restrict__ Xin) {
    int seg = blockIdx.x * 4 + (threadIdx.x >> 6);
    int lane = threadIdx.x & 63;
    int r = seg >> 13;          // /8192
    int dstn = seg & (NNODES - 1);
    float a[8] = {0, 0, 0, 0, 0, 0, 0, 0};
    int s0 = segstart[seg], s1 = segstart[seg + 1];
    for (int t = s0; t < s1; ++t) {
        const float* xs = x + (size_t)esorted[t] * HIDD;
#pragma unroll
        for (int j = 0; j < 8; j++) a[j] += xs[lane + j * 64];
    }
    float iv = inv[seg];
    unsigned short* o = Xin + (size_t)dstn * KSDIM + r * HIDD;
#pragma unroll
    for (int j = 0; j < 8; j++) o[lane + j * 64] = f2b(a[j] * iv);
}

// Copy x fp32 [8192][512] into root columns Xin[:, 4096:4608] as bf16
__global__ void k_rootcopy(const float* __restrict__ x, unsigned short* __restrict__ Xin) {
    int n = blockIdx.x;
    const float* xs = x + (size_t)n * HIDD;
    unsigned short* o = Xin + (size_t)n * KSDIM + NRELS * HIDD;
    for (int j = threadIdx.x; j < HIDD; j += 256) o[j] = f2b(xs[j]);
}

// ---------------------------------------------------------------------------
// bf16 MFMA GEMM: C[M][N] = A[M][K] @ Bt[N][K]^T + bias, optional ReLU
// 128x128 tile, BK=32, 4 waves (2x2), mfma_f32_16x16x32_bf16
// ---------------------------------------------------------------------------
template <int RELU>
__global__ __launch_bounds__(256, 2) void k_gemm(
        const unsigned short* __restrict__ A,   // [M][K] bf16
        const unsigned short* __restrict__ Bt,  // [N][K] bf16
        const float* __restrict__ bias,         // [N]
        float* __restrict__ C,                  // [M][N]
        int M, int N, int K) {
    __shared__ unsigned short As[128 * 32];
    __shared__ unsigned short Bs[128 * 32];
    const int tid = threadIdx.x;
    const int lane = tid & 63, wid = tid >> 6;
    const int tiles_m = M >> 7;
    const int tm = blockIdx.x % tiles_m, tn = blockIdx.x / tiles_m;
    const int m0 = tm << 7, n0 = tn << 7;
    const int wr = wid >> 1, wc = wid & 1;

    f32x4 acc[4][4];
#pragma unroll
    for (int i = 0; i < 4; i++)
#pragma unroll
        for (int j = 0; j < 4; j++) acc[i][j] = (f32x4){0.f, 0.f, 0.f, 0.f};

    // staging: granule g in [0,512): row = g>>2 (128 rows), c = g&3 (4 x 16B per 32-elem row)
    const int g1 = tid + 256;
    const unsigned short* pA0 = A + (size_t)(m0 + (tid >> 2)) * K + (tid & 3) * 8;
    const unsigned short* pA1 = A + (size_t)(m0 + (g1 >> 2)) * K + (g1 & 3) * 8;
    const unsigned short* pB0 = Bt + (size_t)(n0 + (tid >> 2)) * K + (tid & 3) * 8;
    const unsigned short* pB1 = Bt + (size_t)(n0 + (g1 >> 2)) * K + (g1 & 3) * 8;
    // wave-uniform LDS bases (elements); HW adds lane*16B
    unsigned short* ldsA0 = As + (size_t)wid * 512;
    unsigned short* ldsA1 = As + 2048 + (size_t)wid * 512;
    unsigned short* ldsB0 = Bs + (size_t)wid * 512;
    unsigned short* ldsB1 = Bs + 2048 + (size_t)wid * 512;

    const int arow = wr * 64 + (lane & 15);
    const int brow = wc * 64 + (lane & 15);
    const int koff = (lane >> 4) * 8;

    for (int kt = 0; kt < K; kt += 32) {
        if (kt) __syncthreads();
        __builtin_amdgcn_global_load_lds(
            (const __attribute__((address_space(1))) void*)(pA0 + kt),
            (__attribute__((address_space(3))) void*)ldsA0, 16, 0, 0);
        __builtin_amdgcn_global_load_lds(
            (const __attribute__((address_space(1))) void*)(pA1 + kt),
            (__attribute__((address_space(3))) void*)ldsA1, 16, 0, 0);
        __builtin_amdgcn_global_load_lds(
            (const __attribute__((address_space(1))) void*)(pB0 + kt),
            (__attribute__((address_space(3))) void*)ldsB0, 16, 0, 0);
        __builtin_amdgcn_global_load_lds(
            (const __attribute__((address_space(1))) void*)(pB1 + kt),
            (__attribute__((address_space(3))) void*)ldsB1, 16, 0, 0);
        __syncthreads();

        bf16x8 af[4], bf[4];
#pragma unroll
        for (int m = 0; m < 4; m++)
            af[m] = *(const bf16x8*)&As[(arow + m * 16) * 32 + koff];
#pragma unroll
        for (int n = 0; n < 4; n++)
            bf[n] = *(const bf16x8*)&Bs[(brow + n * 16) * 32 + koff];
#pragma unroll
        for (int m = 0; m < 4; m++)
#pragma unroll
            for (int n = 0; n < 4; n++)
                acc[m][n] = __builtin_amdgcn_mfma_f32_16x16x32_bf16(af[m], bf[n], acc[m][n], 0, 0, 0);
    }

    // epilogue: D row = (lane>>4)*4 + reg, col = lane&15
    const int crow0 = m0 + wr * 64 + (lane >> 4) * 4;
    const int ccol0 = n0 + wc * 64 + (lane & 15);
#pragma unroll
    for (int n = 0; n < 4; n++) {
        int col = ccol0 + n * 16;
        float bv = bias[col];
#pragma unroll
        for (int m = 0; m < 4; m++) {
#pragma unroll
            for (int r = 0; r < 4; r++) {
                int row = crow0 + m * 16 + r;
                float v = acc[m][n][r] + bv;
                if (RELU) v = fmaxf(v, 0.f);
                C[(size_t)row * N + col] = v;
            }
        }
    }
}

// ---------------------------------------------------------------------------
// Pool: mean over 128 nodes per graph -> pooled [64][256]
// ---------------------------------------------------------------------------
__global__ void k_pool(const float* __restrict__ x3, float* __restrict__ pooled) {
    int b = blockIdx.x, o = threadIdx.x;
    float s = 0.f;
    for (int i = 0; i < 128; i++) s += x3[(size_t)(b * 128 + i) * OUTD + o];
    pooled[b * OUTD + o] = s * (1.0f / 128.0f);
}

// Classifier: logits = (pooled @ Wc1 + bc1) @ Wc2 + bc2 ; softmax
__global__ void k_classifier(const float* __restrict__ pooled, const float* __restrict__ Wc1,
                             const float* __restrict__ bc1, const float* __restrict__ Wc2,
                             const float* __restrict__ bc2, float* __restrict__ out) {
    __shared__ float h[256];
    __shared__ float lg[2];
    int b = blockIdx.x, o = threadIdx.x;
    const float* p = pooled + b * 256;
    float s = bc1[o];
    for (int i = 0; i < 256; i++) s += p[i] * Wc1[i * 256 + o];
    h[o] = s;
    __syncthreads();
    if (o < 2) {
        float t = bc2[o];
        for (int i = 0; i < 256; i++) t += h[i] * Wc2[i * 2 + o];
        lg[o] = t;
        out[b * 2 + o] = t;
    }
    __syncthreads();
    if (o == 0) {
        float m = fmaxf(lg[0], lg[1]);
        float e0 = expf(lg[0] - m), e1 = expf(lg[1] - m);
        float inv = 1.0f / (e0 + e1);
        out[128 + b * 2 + 0] = e0 * inv;
        out[128 + b * 2 + 1] = e1 * inv;
    }
}

// ---------------------------------------------------------------------------
extern "C" void kernel_launch(void* const* d_in, const int* in_sizes, int n_in,
                              void* d_out, int out_size, void* d_ws, size_t ws_size,
                              hipStream_t stream) {
    const float* box     = (const float*)d_in[0];
    const int*   labels  = (const int*)d_in[1];
    const int*   eidx    = (const int*)d_in[2];
    const int*   etype   = (const int*)d_in[3];
    const float* emb     = (const float*)d_in[5];
    const float* W_lin   = (const float*)d_in[6];
    const float* b_lin   = (const float*)d_in[7];
    const float* rel_W1  = (const float*)d_in[8];
    const float* root_W1 = (const float*)d_in[9];
    const float* b1      = (const float*)d_in[10];
    const float* rel_W2  = (const float*)d_in[11];
    const float* root_W2 = (const float*)d_in[12];
    const float* b2      = (const float*)d_in[13];
    const float* Wc1     = (const float*)d_in[14];
    const float* bc1     = (const float*)d_in[15];
    const float* Wc2     = (const float*)d_in[16];
    const float* bc2     = (const float*)d_in[17];
    const int* esrc = eidx;
    const int* edst = eidx + NEDGES;

    char* ws = (char*)d_ws;
    size_t off = 0;
    auto alloc = [&](size_t bytes) -> char* {
        char* p = ws + off;
        off += (bytes + 255) & ~(size_t)255;
        return p;
    };
    unsigned short* X0   = (unsigned short*)alloc((size_t)NNODES * K0DIM * 2);
    unsigned short* W0t  = (unsigned short*)alloc((size_t)HIDD * K0DIM * 2);
    unsigned short* W1t  = (unsigned short*)alloc((size_t)HIDD * KSDIM * 2);
    unsigned short* W2t  = (unsigned short*)alloc((size_t)OUTD * KSDIM * 2);
    unsigned short* Xin  = (unsigned short*)alloc((size_t)NNODES * KSDIM * 2);
    float* x1      = (float*)alloc((size_t)NNODES * HIDD * 4);
    float* x2      = (float*)alloc((size_t)NNODES * HIDD * 4);
    float* x3      = (float*)alloc((size_t)NNODES * OUTD * 4);
    int*   cnt     = (int*)alloc((size_t)NSEG * 4);
    int*   cursor  = (int*)alloc((size_t)NSEG * 4);
    int*   segst   = (int*)alloc((size_t)(NSEG + 1) * 4);
    float* inv     = (float*)alloc((size_t)NSEG * 4);
    int*   esorted = (int*)alloc((size_t)NEDGES * 4);
    float* pooled  = (float*)alloc((size_t)64 * OUTD * 4);
    if (off > ws_size) return;  // workspace too small; fail loudly via wrong output

    float* out = (float*)d_out;

    // --- CSR + weight prep (independent) ---
    hipMemsetAsync(cnt, 0, NSEG * 4, stream);
    hipMemsetAsync(cursor, 0, NSEG * 4, stream);
    k_build_x0<<<NNODES, 256, 0, stream>>>(box, labels, emb, X0);
    k_transpose<<<dim3(K0DIM / 32, HIDD / 32), 256, 0, stream>>>(W_lin, W0t, HIDD, K0DIM, 0);
    k_transpose<<<dim3(4096 / 32, HIDD / 32), 256, 0, stream>>>(rel_W1, W1t, HIDD, KSDIM, 0);
    k_transpose<<<dim3(HIDD / 32, HIDD / 32), 256, 0, stream>>>(root_W1, W1t, HIDD, KSDIM, 4096);
    k_transpose<<<dim3(4096 / 32, OUTD / 32), 256, 0, stream>>>(rel_W2, W2t, OUTD, KSDIM, 0);
    k_transpose<<<dim3(HIDD / 32, OUTD / 32), 256, 0, stream>>>(root_W2, W2t, OUTD, KSDIM, 4096);
    k_hist<<<NEDGES / 256, 256, 0, stream>>>(etype, edst, cnt);
    k_scan<<<1, 256, 0, stream>>>(cnt, segst);
    k_scatter<<<NEDGES / 256, 256, 0, stream>>>(etype, esrc, edst, segst, cursor, esorted);
    k_inv<<<NSEG / 256, 256, 0, stream>>>(cnt, inv);

    // --- layer 0: x1 = X0 @ W_lin + b_lin ---
    k_gemm<0><<<(NNODES / 128) * (HIDD / 128), 256, 0, stream>>>(X0, W0t, b_lin, x1, NNODES, HIDD, K0DIM);

    // --- RGCN layer 1: x2 = relu([A(x1) | x1] @ [rel_W1; root_W1] + b1) ---
    k_aggregate<<<NSEG / 4, 256, 0, stream>>>(x1, segst, esorted, inv, Xin);
    k_rootcopy<<<NNODES, 256, 0, stream>>>(x1, Xin);
    k_gemm<1><<<(NNODES / 128) * (HIDD / 128), 256, 0, stream>>>(Xin, W1t, b1, x2, NNODES, HIDD, KSDIM);

    // --- RGCN layer 2: x3 = [A(x2) | x2] @ [rel_W2; root_W2] + b2 ---
    k_aggregate<<<NSEG / 4, 256, 0, stream>>>(x2, segst, esorted, inv, Xin);
    k_rootcopy<<<NNODES, 256, 0, stream>>>(x2, Xin);
    k_gemm<0><<<(NNODES / 128) * (OUTD / 128), 256, 0, stream>>>(Xin, W2t, b2, x3, NNODES, OUTD, KSDIM);

    // --- pooling + classifier ---
    k_pool<<<64, 256, 0, stream>>>(x3, pooled);
    k_classifier<<<64, 256, 0, stream>>>(pooled, Wc1, bc1, Wc2, bc2, out);
}

// Round 2
// 380.747 us; speedup vs baseline: 1.2130x; 1.2130x over previous
//
#include <hip/hip_runtime.h>
#include <cstdint>

#define NNODES 8192
#define NEDGES 262144
#define NRELS  8
#define EMBD   256
#define BOXD   1024
#define HIDD   512
#define OUTD   256
#define NSEG   (NRELS * NNODES)      // 65536
#define K0DIM  (BOXD + EMBD)         // 1280
#define KSDIM  (NRELS * HIDD + HIDD) // 4608

using bf16x8 = __attribute__((ext_vector_type(8))) short;
using f32x4  = __attribute__((ext_vector_type(4))) float;
using us4    = __attribute__((ext_vector_type(4))) unsigned short;

__device__ __forceinline__ unsigned short f2b(float f) {
    union { float f; uint32_t u; } v; v.f = f;
    uint32_t r = v.u + 0x7FFFu + ((v.u >> 16) & 1u);
    return (unsigned short)(r >> 16);
}

__device__ __forceinline__ us4 cvt4(f32x4 v) {
    us4 u;
    u[0] = f2b(v[0]); u[1] = f2b(v[1]); u[2] = f2b(v[2]); u[3] = f2b(v[3]);
    return u;
}

// ---------------------------------------------------------------------------
// Build X0 bf16 [8192][1280] = concat(box, emb[labels])  (vectorized)
// ---------------------------------------------------------------------------
__global__ void k_build_x0(const float* __restrict__ box, const int* __restrict__ labels,
                           const float* __restrict__ emb, unsigned short* __restrict__ X0) {
    int n = blockIdx.x;
    int lab = labels[n];
    const f32x4* b = (const f32x4*)(box + (size_t)n * BOXD);
    const f32x4* e = (const f32x4*)(emb + (size_t)lab * EMBD);
    us4* o = (us4*)(X0 + (size_t)n * K0DIM);
    for (int j = threadIdx.x; j < K0DIM / 4; j += 256) {
        f32x4 v = (j < BOXD / 4) ? b[j] : e[j - BOXD / 4];
        o[j] = cvt4(v);
    }
}

// ---------------------------------------------------------------------------
// Tiled transpose fp32 [Ks][No] -> bf16 dst[o][kOff + k], row stride ldDst
// ---------------------------------------------------------------------------
__global__ void k_transpose(const float* __restrict__ src, unsigned short* __restrict__ dst,
                            int No, int ldDst, int kOff) {
    __shared__ float t[32][33];
    int kt = blockIdx.x * 32, ot = blockIdx.y * 32;
    int tx = threadIdx.x & 31, ty = threadIdx.x >> 5; // 32 x 8
#pragma unroll
    for (int i = 0; i < 4; i++) {
        int k = kt + ty + i * 8;
        t[ty + i * 8][tx] = src[(size_t)k * No + ot + tx];
    }
    __syncthreads();
#pragma unroll
    for (int i = 0; i < 4; i++) {
        int o = ot + ty + i * 8;
        dst[(size_t)o * ldDst + kOff + kt + tx] = f2b(t[tx][ty + i * 8]);
    }
}

// ---------------------------------------------------------------------------
// CSR build
// ---------------------------------------------------------------------------
__global__ void k_hist(const int* __restrict__ etype, const int* __restrict__ edst,
                       int* __restrict__ cnt) {
    int e = blockIdx.x * 256 + threadIdx.x;
    if (e >= NEDGES) return;
    atomicAdd(&cnt[etype[e] * NNODES + edst[e]], 1);
}

__global__ void k_scan(const int* __restrict__ cnt, int* __restrict__ segstart) {
    __shared__ int part[256];
    __shared__ int pre[257];
    int t = threadIdx.x;
    int base = t * 256;
    int s = 0;
    for (int i = 0; i < 256; i++) s += cnt[base + i];
    part[t] = s;
    __syncthreads();
    if (t == 0) {
        int a = 0;
        for (int i = 0; i < 256; i++) { pre[i] = a; a += part[i]; }
        pre[256] = a;
    }
    __syncthreads();
    int a = pre[t];
    for (int i = 0; i < 256; i++) { segstart[base + i] = a; a += cnt[base + i]; }
    if (t == 255) segstart[NSEG] = a;
}

__global__ void k_scatter(const int* __restrict__ etype, const int* __restrict__ esrc,
                          const int* __restrict__ edst, const int* __restrict__ segstart,
                          int* __restrict__ cursor, int* __restrict__ esorted) {
    int e = blockIdx.x * 256 + threadIdx.x;
    if (e >= NEDGES) return;
    int key = etype[e] * NNODES + edst[e];
    int pos = atomicAdd(&cursor[key], 1);
    esorted[segstart[key] + pos] = esrc[e];
}

__global__ void k_inv(const int* __restrict__ cnt, float* __restrict__ inv) {
    int s = blockIdx.x * 256 + threadIdx.x;
    if (s >= NSEG) return;
    int c = cnt[s];
    inv[s] = 1.0f / (float)(c > 0 ? c : 1);
}

// ---------------------------------------------------------------------------
// Aggregation: one wave per (rel,dst) segment, float4 loads, 8B bf16 stores.
// ---------------------------------------------------------------------------
__global__ __launch_bounds__(256) void k_aggregate(
        const float* __restrict__ x, const int* __restrict__ segstart,
        const int* __restrict__ esorted, const float* __restrict__ inv,
        unsigned short* __restrict__ Xin) {
    int seg = blockIdx.x * 4 + (threadIdx.x >> 6);
    int lane = threadIdx.x & 63;
    int r = seg >> 13;          // /8192
    int dstn = seg & (NNODES - 1);
    f32x4 a0 = (f32x4){0.f, 0.f, 0.f, 0.f};
    f32x4 a1 = (f32x4){0.f, 0.f, 0.f, 0.f};
    int s0 = segstart[seg], s1 = segstart[seg + 1];
    for (int t = s0; t < s1; ++t) {
        const f32x4* xs = (const f32x4*)(x + (size_t)esorted[t] * HIDD);
        a0 += xs[lane];
        a1 += xs[lane + 64];
    }
    float iv = inv[seg];
    unsigned short* o = Xin + (size_t)dstn * KSDIM + r * HIDD;
    *(us4*)(o + lane * 4)       = cvt4(a0 * iv);
    *(us4*)(o + 256 + lane * 4) = cvt4(a1 * iv);
}

// Copy x fp32 [8192][512] into root columns Xin[:, 4096:4608] as bf16
__global__ void k_rootcopy(const float* __restrict__ x, unsigned short* __restrict__ Xin) {
    int n = blockIdx.x, j = threadIdx.x;  // 128 threads
    f32x4 v = ((const f32x4*)(x + (size_t)n * HIDD))[j];
    *(us4*)(Xin + (size_t)n * KSDIM + NRELS * HIDD + j * 4) = cvt4(v);
}

// ---------------------------------------------------------------------------
// bf16 MFMA GEMM, split-K partials: P[split] = A[:, ks:ke] @ Bt[:, ks:ke]^T
// 128x128 tile, BK=32, 8 waves (2x4), LDS XOR-swizzled (slot = chunk^((row>>1)&3))
// ---------------------------------------------------------------------------
__global__ __launch_bounds__(512, 4) void k_gemm(
        const unsigned short* __restrict__ A,   // [M][K] bf16
        const unsigned short* __restrict__ Bt,  // [N][K] bf16
        float* __restrict__ P,                  // [S][M][N] partials
        int M, int N, int K, int Kc) {
    __shared__ unsigned short As[128 * 32];
    __shared__ unsigned short Bs[128 * 32];
    const int tid = threadIdx.x;
    const int lane = tid & 63, wid = tid >> 6;
    const int tiles_m = M >> 7;
    const int tm = blockIdx.x % tiles_m, tn = blockIdx.x / tiles_m;
    const int m0 = tm << 7, n0 = tn << 7;
    const int wr = wid >> 2, wc = wid & 3;       // 2 x 4 wave grid
    const int split = blockIdx.y;
    const int k0 = split * Kc;

    f32x4 acc[4][2];
#pragma unroll
    for (int i = 0; i < 4; i++)
#pragma unroll
        for (int j = 0; j < 2; j++) acc[i][j] = (f32x4){0.f, 0.f, 0.f, 0.f};

    // staging: thread g stages LDS row g>>2, slot g&3; inverse-swizzled global chunk
    const int rg = tid >> 2;
    const int cg = (tid & 3) ^ ((tid >> 3) & 3);
    const unsigned short* pA = A  + (size_t)(m0 + rg) * K + k0 + cg * 8;
    const unsigned short* pB = Bt + (size_t)(n0 + rg) * K + k0 + cg * 8;
    unsigned short* ldsA = As + wid * 512;  // wave-uniform; HW adds lane*16B
    unsigned short* ldsB = Bs + wid * 512;

    // read: row r, logical chunk k=lane>>4 lives at slot k ^ ((r>>1)&3);
    // (r>>1)&3 == (lane>>1)&3 for all fragment rows (offsets are mult. of 16)
    const int xoff = ((lane >> 4) ^ ((lane >> 1) & 3)) * 8;
    const int ar = wr * 64 + (lane & 15);
    const int br = wc * 32 + (lane & 15);

    for (int kt = 0; kt < Kc; kt += 32) {
        if (kt) __syncthreads();
        __builtin_amdgcn_global_load_lds(
            (const __attribute__((address_space(1))) void*)(pA + kt),
            (__attribute__((address_space(3))) void*)ldsA, 16, 0, 0);
        __builtin_amdgcn_global_load_lds(
            (const __attribute__((address_space(1))) void*)(pB + kt),
            (__attribute__((address_space(3))) void*)ldsB, 16, 0, 0);
        __syncthreads();

        bf16x8 af[4], bfr[2];
#pragma unroll
        for (int m = 0; m < 4; m++)
            af[m] = *(const bf16x8*)&As[(ar + m * 16) * 32 + xoff];
#pragma unroll
        for (int n = 0; n < 2; n++)
            bfr[n] = *(const bf16x8*)&Bs[(br + n * 16) * 32 + xoff];
#pragma unroll
        for (int m = 0; m < 4; m++)
#pragma unroll
            for (int n = 0; n < 2; n++)
                acc[m][n] = __builtin_amdgcn_mfma_f32_16x16x32_bf16(af[m], bfr[n], acc[m][n], 0, 0, 0);
    }

    float* Pout = P + (size_t)split * M * N;
    const int crow0 = m0 + wr * 64 + (lane >> 4) * 4;
    const int ccol0 = n0 + wc * 32 + (lane & 15);
#pragma unroll
    for (int n = 0; n < 2; n++) {
        int col = ccol0 + n * 16;
#pragma unroll
        for (int m = 0; m < 4; m++)
#pragma unroll
            for (int r = 0; r < 4; r++)
                Pout[(size_t)(crow0 + m * 16 + r) * N + col] = acc[m][n][r];
    }
}

// ---------------------------------------------------------------------------
// Reduce split-K partials + bias (+ReLU). out may alias P (elementwise).
// ---------------------------------------------------------------------------
template <int S, int RELU>
__global__ void k_reduce(const float* P, const float* __restrict__ bias,
                         float* out, int MN, int N) {
    int idx = (blockIdx.x * 256 + threadIdx.x) * 4;
    f32x4 v = *(const f32x4*)&P[idx];
#pragma unroll
    for (int s = 1; s < S; s++) v += *(const f32x4*)&P[(size_t)s * MN + idx];
    v += *(const f32x4*)&bias[idx & (N - 1)];
    if (RELU) {
#pragma unroll
        for (int j = 0; j < 4; j++) v[j] = fmaxf(v[j], 0.f);
    }
    *(f32x4*)&out[idx] = v;
}

// ---------------------------------------------------------------------------
// Pool: mean over 128 nodes per graph -> pooled [64][256]
// ---------------------------------------------------------------------------
__global__ void k_pool(const float* __restrict__ x3, float* __restrict__ pooled) {
    int b = blockIdx.x, o = threadIdx.x;
    float s = 0.f;
    for (int i = 0; i < 128; i++) s += x3[(size_t)(b * 128 + i) * OUTD + o];
    pooled[b * OUTD + o] = s * (1.0f / 128.0f);
}

// Classifier: logits = (pooled @ Wc1 + bc1) @ Wc2 + bc2 ; softmax
__global__ void k_classifier(const float* __restrict__ pooled, const float* __restrict__ Wc1,
                             const float* __restrict__ bc1, const float* __restrict__ Wc2,
                             const float* __restrict__ bc2, float* __restrict__ out) {
    __shared__ float h[256];
    __shared__ float lg[2];
    int b = blockIdx.x, o = threadIdx.x;
    const float* p = pooled + b * 256;
    float s = bc1[o];
    for (int i = 0; i < 256; i++) s += p[i] * Wc1[i * 256 + o];
    h[o] = s;
    __syncthreads();
    if (o < 2) {
        float t = bc2[o];
        for (int i = 0; i < 256; i++) t += h[i] * Wc2[i * 2 + o];
        lg[o] = t;
        out[b * 2 + o] = t;
    }
    __syncthreads();
    if (o == 0) {
        float m = fmaxf(lg[0], lg[1]);
        float e0 = expf(lg[0] - m), e1 = expf(lg[1] - m);
        float inv = 1.0f / (e0 + e1);
        out[128 + b * 2 + 0] = e0 * inv;
        out[128 + b * 2 + 1] = e1 * inv;
    }
}

// ---------------------------------------------------------------------------
extern "C" void kernel_launch(void* const* d_in, const int* in_sizes, int n_in,
                              void* d_out, int out_size, void* d_ws, size_t ws_size,
                              hipStream_t stream) {
    const float* box     = (const float*)d_in[0];
    const int*   labels  = (const int*)d_in[1];
    const int*   eidx    = (const int*)d_in[2];
    const int*   etype   = (const int*)d_in[3];
    const float* emb     = (const float*)d_in[5];
    const float* W_lin   = (const float*)d_in[6];
    const float* b_lin   = (const float*)d_in[7];
    const float* rel_W1  = (const float*)d_in[8];
    const float* root_W1 = (const float*)d_in[9];
    const float* b1      = (const float*)d_in[10];
    const float* rel_W2  = (const float*)d_in[11];
    const float* root_W2 = (const float*)d_in[12];
    const float* b2      = (const float*)d_in[13];
    const float* Wc1     = (const float*)d_in[14];
    const float* bc1     = (const float*)d_in[15];
    const float* Wc2     = (const float*)d_in[16];
    const float* bc2     = (const float*)d_in[17];
    const int* esrc = eidx;
    const int* edst = eidx + NEDGES;

    char* ws = (char*)d_ws;
    size_t off = 0;
    auto alloc = [&](size_t bytes) -> char* {
        char* p = ws + off;
        off += (bytes + 255) & ~(size_t)255;
        return p;
    };
    // Split-K partial region (32 MB). x1/x2/x3 alias its base:
    //   - partials for layer L are written only after layer L's inputs were consumed
    //   - k_reduce reads P[s][i] then writes out[i] (elementwise, same index) so
    //     out aliasing P[0] is safe.
    float* Pp = (float*)alloc((size_t)2 * NNODES * HIDD * 4);  // 32 MB
    float* x1 = Pp;
    float* x2 = Pp;
    float* x3 = Pp;
    unsigned short* X0   = (unsigned short*)alloc((size_t)NNODES * K0DIM * 2);
    unsigned short* W0t  = (unsigned short*)alloc((size_t)HIDD * K0DIM * 2);
    unsigned short* W1t  = (unsigned short*)alloc((size_t)HIDD * KSDIM * 2);
    unsigned short* W2t  = (unsigned short*)alloc((size_t)OUTD * KSDIM * 2);
    unsigned short* Xin  = (unsigned short*)alloc((size_t)NNODES * KSDIM * 2);
    int*   cnt     = (int*)alloc((size_t)NSEG * 4);
    int*   cursor  = (int*)alloc((size_t)NSEG * 4);
    int*   segst   = (int*)alloc((size_t)(NSEG + 1) * 4);
    float* inv     = (float*)alloc((size_t)NSEG * 4);
    int*   esorted = (int*)alloc((size_t)NEDGES * 4);
    float* pooled  = (float*)alloc((size_t)64 * OUTD * 4);
    if (off > ws_size) return;

    float* out = (float*)d_out;

    // --- CSR + weight prep (independent) ---
    hipMemsetAsync(cnt, 0, NSEG * 4, stream);
    hipMemsetAsync(cursor, 0, NSEG * 4, stream);
    k_build_x0<<<NNODES, 256, 0, stream>>>(box, labels, emb, X0);
    k_transpose<<<dim3(K0DIM / 32, HIDD / 32), 256, 0, stream>>>(W_lin, W0t, HIDD, K0DIM, 0);
    k_transpose<<<dim3(4096 / 32, HIDD / 32), 256, 0, stream>>>(rel_W1, W1t, HIDD, KSDIM, 0);
    k_transpose<<<dim3(HIDD / 32, HIDD / 32), 256, 0, stream>>>(root_W1, W1t, HIDD, KSDIM, 4096);
    k_transpose<<<dim3(4096 / 32, OUTD / 32), 256, 0, stream>>>(rel_W2, W2t, OUTD, KSDIM, 0);
    k_transpose<<<dim3(HIDD / 32, OUTD / 32), 256, 0, stream>>>(root_W2, W2t, OUTD, KSDIM, 4096);
    k_hist<<<NEDGES / 256, 256, 0, stream>>>(etype, edst, cnt);
    k_scan<<<1, 256, 0, stream>>>(cnt, segst);
    k_scatter<<<NEDGES / 256, 256, 0, stream>>>(etype, esrc, edst, segst, cursor, esorted);
    k_inv<<<NSEG / 256, 256, 0, stream>>>(cnt, inv);

    // --- layer 0: x1 = X0 @ W_lin + b_lin  (S=2, Kc=640) ---
    k_gemm<<<dim3((NNODES / 128) * (HIDD / 128), 2), 512, 0, stream>>>(
        X0, W0t, Pp, NNODES, HIDD, K0DIM, K0DIM / 2);
    k_reduce<2, 0><<<(NNODES * HIDD) / 1024, 256, 0, stream>>>(
        Pp, b_lin, x1, NNODES * HIDD, HIDD);

    // --- RGCN layer 1: x2 = relu([A(x1) | x1] @ [rel_W1; root_W1] + b1)  (S=2, Kc=2304) ---
    k_aggregate<<<NSEG / 4, 256, 0, stream>>>(x1, segst, esorted, inv, Xin);
    k_rootcopy<<<NNODES, 128, 0, stream>>>(x1, Xin);
    k_gemm<<<dim3((NNODES / 128) * (HIDD / 128), 2), 512, 0, stream>>>(
        Xin, W1t, Pp, NNODES, HIDD, KSDIM, KSDIM / 2);
    k_reduce<2, 1><<<(NNODES * HIDD) / 1024, 256, 0, stream>>>(
        Pp, b1, x2, NNODES * HIDD, HIDD);

    // --- RGCN layer 2: x3 = [A(x2) | x2] @ [rel_W2; root_W2] + b2  (S=4, Kc=1152) ---
    k_aggregate<<<NSEG / 4, 256, 0, stream>>>(x2, segst, esorted, inv, Xin);
    k_rootcopy<<<NNODES, 128, 0, stream>>>(x2, Xin);
    k_gemm<<<dim3((NNODES / 128) * (OUTD / 128), 4), 512, 0, stream>>>(
        Xin, W2t, Pp, NNODES, OUTD, KSDIM, KSDIM / 4);
    k_reduce<4, 0><<<(NNODES * OUTD) / 1024, 256, 0, stream>>>(
        Pp, b2, x3, NNODES * OUTD, OUTD);

    // --- pooling + classifier ---
    k_pool<<<64, 256, 0, stream>>>(x3, pooled);
    k_classifier<<<64, 256, 0, stream>>>(pooled, Wc1, bc1, Wc2, bc2, out);
}

// Round 3
// 294.376 us; speedup vs baseline: 1.5688x; 1.2934x over previous
//
#include <hip/hip_runtime.h>
#include <cstdint>

#define NNODES 8192
#define NEDGES 262144
#define NRELS  8
#define EMBD   256
#define BOXD   1024
#define HIDD   512
#define OUTD   256
#define NSEG   (NRELS * NNODES)      // 65536
#define K0DIM  (BOXD + EMBD)         // 1280
#define KSDIM  (NRELS * HIDD + HIDD) // 4608

using bf16x8 = __attribute__((ext_vector_type(8))) short;
using f32x4  = __attribute__((ext_vector_type(4))) float;
using us4    = __attribute__((ext_vector_type(4))) unsigned short;

__device__ __forceinline__ unsigned short f2b(float f) {
    union { float f; uint32_t u; } v; v.f = f;
    uint32_t r = v.u + 0x7FFFu + ((v.u >> 16) & 1u);
    return (unsigned short)(r >> 16);
}

__device__ __forceinline__ us4 cvt4(f32x4 v) {
    us4 u;
    u[0] = f2b(v[0]); u[1] = f2b(v[1]); u[2] = f2b(v[2]); u[3] = f2b(v[3]);
    return u;
}

__device__ __forceinline__ float b2f_lo(uint32_t w) {
    union { uint32_t u; float f; } v; v.u = w << 16; return v.f;
}
__device__ __forceinline__ float b2f_hi(uint32_t w) {
    union { uint32_t u; float f; } v; v.u = w & 0xffff0000u; return v.f;
}

// ---------------------------------------------------------------------------
// Build X0 bf16 [8192][1280] = concat(box, emb[labels])
// ---------------------------------------------------------------------------
__global__ void k_build_x0(const float* __restrict__ box, const int* __restrict__ labels,
                           const float* __restrict__ emb, unsigned short* __restrict__ X0) {
    int n = blockIdx.x;
    int lab = labels[n];
    const f32x4* b = (const f32x4*)(box + (size_t)n * BOXD);
    const f32x4* e = (const f32x4*)(emb + (size_t)lab * EMBD);
    us4* o = (us4*)(X0 + (size_t)n * K0DIM);
    for (int j = threadIdx.x; j < K0DIM / 4; j += 256) {
        f32x4 v = (j < BOXD / 4) ? b[j] : e[j - BOXD / 4];
        o[j] = cvt4(v);
    }
}

// ---------------------------------------------------------------------------
// Tiled transpose fp32 [Ks][No] -> bf16 dst[o][kOff + k], row stride ldDst
// ---------------------------------------------------------------------------
__global__ void k_transpose(const float* __restrict__ src, unsigned short* __restrict__ dst,
                            int No, int ldDst, int kOff) {
    __shared__ float t[32][33];
    int kt = blockIdx.x * 32, ot = blockIdx.y * 32;
    int tx = threadIdx.x & 31, ty = threadIdx.x >> 5; // 32 x 8
#pragma unroll
    for (int i = 0; i < 4; i++) {
        int k = kt + ty + i * 8;
        t[ty + i * 8][tx] = src[(size_t)k * No + ot + tx];
    }
    __syncthreads();
#pragma unroll
    for (int i = 0; i < 4; i++) {
        int o = ot + ty + i * 8;
        dst[(size_t)o * ldDst + kOff + kt + tx] = f2b(t[tx][ty + i * 8]);
    }
}

// ---------------------------------------------------------------------------
// CSR build
// ---------------------------------------------------------------------------
__global__ void k_hist(const int* __restrict__ etype, const int* __restrict__ edst,
                       int* __restrict__ cnt) {
    int e = blockIdx.x * 256 + threadIdx.x;
    if (e >= NEDGES) return;
    atomicAdd(&cnt[etype[e] * NNODES + edst[e]], 1);
}

__global__ void k_scan(const int* __restrict__ cnt, int* __restrict__ segstart) {
    __shared__ int part[256];
    __shared__ int pre[257];
    int t = threadIdx.x;
    int base = t * 256;
    int s = 0;
    for (int i = 0; i < 256; i++) s += cnt[base + i];
    part[t] = s;
    __syncthreads();
    if (t == 0) {
        int a = 0;
        for (int i = 0; i < 256; i++) { pre[i] = a; a += part[i]; }
        pre[256] = a;
    }
    __syncthreads();
    int a = pre[t];
    for (int i = 0; i < 256; i++) { segstart[base + i] = a; a += cnt[base + i]; }
    if (t == 255) segstart[NSEG] = a;
}

__global__ void k_scatter(const int* __restrict__ etype, const int* __restrict__ esrc,
                          const int* __restrict__ edst, const int* __restrict__ segstart,
                          int* __restrict__ cursor, int* __restrict__ esorted) {
    int e = blockIdx.x * 256 + threadIdx.x;
    if (e >= NEDGES) return;
    int key = etype[e] * NNODES + edst[e];
    int pos = atomicAdd(&cursor[key], 1);
    esorted[segstart[key] + pos] = esrc[e];
}

__global__ void k_inv(const int* __restrict__ cnt, float* __restrict__ inv) {
    int s = blockIdx.x * 256 + threadIdx.x;
    if (s >= NSEG) return;
    int c = cnt[s];
    inv[s] = 1.0f / (float)(c > 0 ? c : 1);
}

// ---------------------------------------------------------------------------
// Aggregation: one wave per (rel,dst) segment; bf16 x rows (16B/lane/edge),
// fp32 accumulate, 2-edge unroll for latency overlap.
// ---------------------------------------------------------------------------
__global__ __launch_bounds__(256) void k_aggregate(
        const unsigned short* __restrict__ x, const int* __restrict__ segstart,
        const int* __restrict__ esorted, const float* __restrict__ inv,
        unsigned short* __restrict__ Xin) {
    int seg = blockIdx.x * 4 + (threadIdx.x >> 6);
    int lane = threadIdx.x & 63;
    int r = seg >> 13;          // /8192
    int dstn = seg & (NNODES - 1);
    float a[8] = {0, 0, 0, 0, 0, 0, 0, 0};
    float b[8] = {0, 0, 0, 0, 0, 0, 0, 0};
    int s0 = segstart[seg], s1 = segstart[seg + 1];
    int t = s0;
    for (; t + 2 <= s1; t += 2) {
        uint4 v0 = *(const uint4*)(x + (size_t)esorted[t] * HIDD + lane * 8);
        uint4 v1 = *(const uint4*)(x + (size_t)esorted[t + 1] * HIDD + lane * 8);
        a[0] += b2f_lo(v0.x); a[1] += b2f_hi(v0.x);
        a[2] += b2f_lo(v0.y); a[3] += b2f_hi(v0.y);
        a[4] += b2f_lo(v0.z); a[5] += b2f_hi(v0.z);
        a[6] += b2f_lo(v0.w); a[7] += b2f_hi(v0.w);
        b[0] += b2f_lo(v1.x); b[1] += b2f_hi(v1.x);
        b[2] += b2f_lo(v1.y); b[3] += b2f_hi(v1.y);
        b[4] += b2f_lo(v1.z); b[5] += b2f_hi(v1.z);
        b[6] += b2f_lo(v1.w); b[7] += b2f_hi(v1.w);
    }
    if (t < s1) {
        uint4 v0 = *(const uint4*)(x + (size_t)esorted[t] * HIDD + lane * 8);
        a[0] += b2f_lo(v0.x); a[1] += b2f_hi(v0.x);
        a[2] += b2f_lo(v0.y); a[3] += b2f_hi(v0.y);
        a[4] += b2f_lo(v0.z); a[5] += b2f_hi(v0.z);
        a[6] += b2f_lo(v0.w); a[7] += b2f_hi(v0.w);
    }
    float iv = inv[seg];
#pragma unroll
    for (int j = 0; j < 8; j++) a[j] = (a[j] + b[j]) * iv;
    uint4 u;
    u.x = (uint32_t)f2b(a[0]) | ((uint32_t)f2b(a[1]) << 16);
    u.y = (uint32_t)f2b(a[2]) | ((uint32_t)f2b(a[3]) << 16);
    u.z = (uint32_t)f2b(a[4]) | ((uint32_t)f2b(a[5]) << 16);
    u.w = (uint32_t)f2b(a[6]) | ((uint32_t)f2b(a[7]) << 16);
    *(uint4*)(Xin + (size_t)dstn * KSDIM + r * HIDD + lane * 8) = u;
}

// ---------------------------------------------------------------------------
// bf16 MFMA GEMM, split-K partials. 128x128 tile, BK=64, 8 waves (2x4),
// LDS [128][64] per buffer, XOR swizzle slot = chunk ^ (row&7) (16B slots),
// explicit double-buffer + raw s_barrier (one barrier per K-tile).
// ---------------------------------------------------------------------------
__global__ __launch_bounds__(512, 4) void k_gemm(
        const unsigned short* __restrict__ A,   // [M][K] bf16
        const unsigned short* __restrict__ Bt,  // [N][K] bf16
        float* __restrict__ P,                  // [S][M][N] partials
        int M, int N, int K, int Kc) {
    __shared__ unsigned short As[2][128 * 64];
    __shared__ unsigned short Bs[2][128 * 64];
    const int tid = threadIdx.x;
    const int lane = tid & 63, wid = tid >> 6;
    const int tiles_m = M >> 7;
    const int tm = blockIdx.x % tiles_m, tn = blockIdx.x / tiles_m;
    const int m0 = tm << 7, n0 = tn << 7;
    const int wr = wid >> 2, wc = wid & 3;       // 2 x 4 wave grid
    const int k0 = blockIdx.y * Kc;

    f32x4 acc[4][2];
#pragma unroll
    for (int i = 0; i < 4; i++)
#pragma unroll
        for (int j = 0; j < 2; j++) acc[i][j] = (f32x4){0.f, 0.f, 0.f, 0.f};

    // staging: thread stages rows {tid>>3, 64+(tid>>3)}, slot tid&7;
    // LDS slot s of row r holds global chunk s^(r&7) -> source chunk inverse-swizzled
    const int rowg = tid >> 3;
    const int srcc = (tid & 7) ^ (rowg & 7);
    const unsigned short* gA = A  + (size_t)(m0 + rowg) * K + k0 + srcc * 8;
    const unsigned short* gB = Bt + (size_t)(n0 + rowg) * K + k0 + srcc * 8;
    const int ldsbase = wid * 512;  // + i*4096 ; HW adds lane*16B

    auto stage = [&](int bsel, int kt) {
#pragma unroll
        for (int i = 0; i < 2; ++i) {
            __builtin_amdgcn_global_load_lds(
                (const __attribute__((address_space(1))) void*)(gA + kt + i * 64 * K),
                (__attribute__((address_space(3))) void*)&As[bsel][i * 4096 + ldsbase], 16, 0, 0);
            __builtin_amdgcn_global_load_lds(
                (const __attribute__((address_space(1))) void*)(gB + kt + i * 64 * K),
                (__attribute__((address_space(3))) void*)&Bs[bsel][i * 4096 + ldsbase], 16, 0, 0);
        }
    };

    const int arow = wr * 64 + (lane & 15);
    const int brow = wc * 32 + (lane & 15);
    const int l7 = lane & 7;
    const int c0 = lane >> 4;   // 0..3

    const int nt = Kc >> 6;
    int cur = 0;
    stage(0, 0);
    asm volatile("s_waitcnt vmcnt(0)" ::: "memory");
    __builtin_amdgcn_s_barrier();

    for (int t = 0; t < nt; ++t) {
        if (t + 1 < nt) stage(cur ^ 1, (t + 1) * 64);
#pragma unroll
        for (int s4 = 0; s4 < 2; ++s4) {
            const int slot = (c0 + s4 * 4) ^ l7;
            bf16x8 af[4], bfr[2];
#pragma unroll
            for (int m = 0; m < 4; m++)
                af[m] = *(const bf16x8*)&As[cur][(arow + m * 16) * 64 + slot * 8];
#pragma unroll
            for (int n = 0; n < 2; n++)
                bfr[n] = *(const bf16x8*)&Bs[cur][(brow + n * 16) * 64 + slot * 8];
#pragma unroll
            for (int m = 0; m < 4; m++)
#pragma unroll
                for (int n = 0; n < 2; n++)
                    acc[m][n] = __builtin_amdgcn_mfma_f32_16x16x32_bf16(af[m], bfr[n], acc[m][n], 0, 0, 0);
        }
        if (t + 1 < nt) {
            asm volatile("s_waitcnt vmcnt(0)" ::: "memory");
            __builtin_amdgcn_s_barrier();
            cur ^= 1;
        }
    }

    float* Pout = P + (size_t)blockIdx.y * M * N;
    const int crow0 = m0 + wr * 64 + (lane >> 4) * 4;
    const int ccol0 = n0 + wc * 32 + (lane & 15);
#pragma unroll
    for (int n = 0; n < 2; n++) {
        int col = ccol0 + n * 16;
#pragma unroll
        for (int m = 0; m < 4; m++)
#pragma unroll
            for (int r = 0; r < 4; r++)
                Pout[(size_t)(crow0 + m * 16 + r) * N + col] = acc[m][n][r];
    }
}

// ---------------------------------------------------------------------------
// Reduce S=2 partials + bias (+ReLU) -> bf16 x AND Xin root columns (N=512)
// ---------------------------------------------------------------------------
template <int RELU>
__global__ void k_reduce_bf(const float* __restrict__ P, const float* __restrict__ bias,
                            unsigned short* __restrict__ xbf, unsigned short* __restrict__ Xin,
                            int MN) {
    int idx = (blockIdx.x * 256 + threadIdx.x) * 4;
    f32x4 v = *(const f32x4*)&P[idx];
    v += *(const f32x4*)&P[(size_t)MN + idx];
    v += *(const f32x4*)&bias[idx & 511];
    if (RELU) {
#pragma unroll
        for (int j = 0; j < 4; j++) v[j] = fmaxf(v[j], 0.f);
    }
    us4 u = cvt4(v);
    *(us4*)&xbf[idx] = u;
    int row = idx >> 9, col = idx & 511;
    *(us4*)&Xin[(size_t)row * KSDIM + NRELS * HIDD + col] = u;
}

// Reduce S=4 partials + bias -> fp32 out (layer 2; out may alias P[0])
__global__ void k_reduce4(const float* P, const float* __restrict__ bias,
                          float* out, int MN, int N) {
    int idx = (blockIdx.x * 256 + threadIdx.x) * 4;
    f32x4 v = *(const f32x4*)&P[idx];
#pragma unroll
    for (int s = 1; s < 4; s++) v += *(const f32x4*)&P[(size_t)s * MN + idx];
    v += *(const f32x4*)&bias[idx & (N - 1)];
    *(f32x4*)&out[idx] = v;
}

// ---------------------------------------------------------------------------
// Pool: mean over 128 nodes per graph -> pooled [64][256]
// ---------------------------------------------------------------------------
__global__ void k_pool(const float* __restrict__ x3, float* __restrict__ pooled) {
    int b = blockIdx.x, o = threadIdx.x;
    float s = 0.f;
    for (int i = 0; i < 128; i++) s += x3[(size_t)(b * 128 + i) * OUTD + o];
    pooled[b * OUTD + o] = s * (1.0f / 128.0f);
}

// Classifier: logits = (pooled @ Wc1 + bc1) @ Wc2 + bc2 ; softmax
__global__ void k_classifier(const float* __restrict__ pooled, const float* __restrict__ Wc1,
                             const float* __restrict__ bc1, const float* __restrict__ Wc2,
                             const float* __restrict__ bc2, float* __restrict__ out) {
    __shared__ float h[256];
    __shared__ float lg[2];
    int b = blockIdx.x, o = threadIdx.x;
    const float* p = pooled + b * 256;
    float s = bc1[o];
    for (int i = 0; i < 256; i++) s += p[i] * Wc1[i * 256 + o];
    h[o] = s;
    __syncthreads();
    if (o < 2) {
        float t = bc2[o];
        for (int i = 0; i < 256; i++) t += h[i] * Wc2[i * 2 + o];
        lg[o] = t;
        out[b * 2 + o] = t;
    }
    __syncthreads();
    if (o == 0) {
        float m = fmaxf(lg[0], lg[1]);
        float e0 = expf(lg[0] - m), e1 = expf(lg[1] - m);
        float inv = 1.0f / (e0 + e1);
        out[128 + b * 2 + 0] = e0 * inv;
        out[128 + b * 2 + 1] = e1 * inv;
    }
}

// ---------------------------------------------------------------------------
extern "C" void kernel_launch(void* const* d_in, const int* in_sizes, int n_in,
                              void* d_out, int out_size, void* d_ws, size_t ws_size,
                              hipStream_t stream) {
    const float* box     = (const float*)d_in[0];
    const int*   labels  = (const int*)d_in[1];
    const int*   eidx    = (const int*)d_in[2];
    const int*   etype   = (const int*)d_in[3];
    const float* emb     = (const float*)d_in[5];
    const float* W_lin   = (const float*)d_in[6];
    const float* b_lin   = (const float*)d_in[7];
    const float* rel_W1  = (const float*)d_in[8];
    const float* root_W1 = (const float*)d_in[9];
    const float* b1      = (const float*)d_in[10];
    const float* rel_W2  = (const float*)d_in[11];
    const float* root_W2 = (const float*)d_in[12];
    const float* b2      = (const float*)d_in[13];
    const float* Wc1     = (const float*)d_in[14];
    const float* bc1     = (const float*)d_in[15];
    const float* Wc2     = (const float*)d_in[16];
    const float* bc2     = (const float*)d_in[17];
    const int* esrc = eidx;
    const int* edst = eidx + NEDGES;

    char* ws = (char*)d_ws;
    size_t off = 0;
    auto alloc = [&](size_t bytes) -> char* {
        char* p = ws + off;
        off += (bytes + 255) & ~(size_t)255;
        return p;
    };
    // Split-K partial region (32 MB); x3 aliases it (elementwise reduce, safe).
    float* Pp = (float*)alloc((size_t)2 * NNODES * HIDD * 4);
    float* x3 = Pp;
    unsigned short* X0   = (unsigned short*)alloc((size_t)NNODES * K0DIM * 2);
    // xbf (bf16 x1/x2, 8 MB) aliases X0 (20 MB): X0 is dead after the layer-0
    // GEMM, which completes before the first k_reduce_bf writes xbf.
    unsigned short* xbf  = X0;
    unsigned short* W0t  = (unsigned short*)alloc((size_t)HIDD * K0DIM * 2);
    unsigned short* W1t  = (unsigned short*)alloc((size_t)HIDD * KSDIM * 2);
    unsigned short* W2t  = (unsigned short*)alloc((size_t)OUTD * KSDIM * 2);
    unsigned short* Xin  = (unsigned short*)alloc((size_t)NNODES * KSDIM * 2);
    int*   cnt     = (int*)alloc((size_t)NSEG * 4);
    int*   cursor  = (int*)alloc((size_t)NSEG * 4);
    int*   segst   = (int*)alloc((size_t)(NSEG + 1) * 4);
    float* inv     = (float*)alloc((size_t)NSEG * 4);
    int*   esorted = (int*)alloc((size_t)NEDGES * 4);
    float* pooled  = (float*)alloc((size_t)64 * OUTD * 4);
    if (off > ws_size) return;

    float* out = (float*)d_out;

    // --- CSR + weight prep ---
    hipMemsetAsync(cnt, 0, NSEG * 4, stream);
    hipMemsetAsync(cursor, 0, NSEG * 4, stream);
    k_build_x0<<<NNODES, 256, 0, stream>>>(box, labels, emb, X0);
    k_transpose<<<dim3(K0DIM / 32, HIDD / 32), 256, 0, stream>>>(W_lin, W0t, HIDD, K0DIM, 0);
    k_transpose<<<dim3(4096 / 32, HIDD / 32), 256, 0, stream>>>(rel_W1, W1t, HIDD, KSDIM, 0);
    k_transpose<<<dim3(HIDD / 32, HIDD / 32), 256, 0, stream>>>(root_W1, W1t, HIDD, KSDIM, 4096);
    k_transpose<<<dim3(4096 / 32, OUTD / 32), 256, 0, stream>>>(rel_W2, W2t, OUTD, KSDIM, 0);
    k_transpose<<<dim3(HIDD / 32, OUTD / 32), 256, 0, stream>>>(root_W2, W2t, OUTD, KSDIM, 4096);
    k_hist<<<NEDGES / 256, 256, 0, stream>>>(etype, edst, cnt);
    k_scan<<<1, 256, 0, stream>>>(cnt, segst);
    k_scatter<<<NEDGES / 256, 256, 0, stream>>>(etype, esrc, edst, segst, cursor, esorted);
    k_inv<<<NSEG / 256, 256, 0, stream>>>(cnt, inv);

    // --- layer 0: x1 = X0 @ W_lin + b_lin  (S=2, Kc=640) ---
    k_gemm<<<dim3((NNODES / 128) * (HIDD / 128), 2), 512, 0, stream>>>(
        X0, W0t, Pp, NNODES, HIDD, K0DIM, K0DIM / 2);
    k_reduce_bf<0><<<(NNODES * HIDD) / 1024, 256, 0, stream>>>(
        Pp, b_lin, xbf, Xin, NNODES * HIDD);

    // --- RGCN layer 1 (S=2, Kc=2304) ---
    k_aggregate<<<NSEG / 4, 256, 0, stream>>>(xbf, segst, esorted, inv, Xin);
    k_gemm<<<dim3((NNODES / 128) * (HIDD / 128), 2), 512, 0, stream>>>(
        Xin, W1t, Pp, NNODES, HIDD, KSDIM, KSDIM / 2);
    k_reduce_bf<1><<<(NNODES * HIDD) / 1024, 256, 0, stream>>>(
        Pp, b1, xbf, Xin, NNODES * HIDD);

    // --- RGCN layer 2 (S=4, Kc=1152) ---
    k_aggregate<<<NSEG / 4, 256, 0, stream>>>(xbf, segst, esorted, inv, Xin);
    k_gemm<<<dim3((NNODES / 128) * (OUTD / 128), 4), 512, 0, stream>>>(
        Xin, W2t, Pp, NNODES, OUTD, KSDIM, KSDIM / 4);
    k_reduce4<<<(NNODES * OUTD) / 1024, 256, 0, stream>>>(
        Pp, b2, x3, NNODES * OUTD, OUTD);

    // --- pooling + classifier ---
    k_pool<<<64, 256, 0, stream>>>(x3, pooled);
    k_classifier<<<64, 256, 0, stream>>>(pooled, Wc1, bc1, Wc2, bc2, out);
}

// Round 4
// 281.969 us; speedup vs baseline: 1.6379x; 1.0440x over previous
//
#include <hip/hip_runtime.h>
#include <cstdint>

#define NNODES 8192
#define NEDGES 262144
#define NRELS  8
#define EMBD   256
#define BOXD   1024
#define HIDD   512
#define OUTD   256
#define NSEG   (NRELS * NNODES)      // 65536
#define K0DIM  (BOXD + EMBD)         // 1280
#define KSDIM  (NRELS * HIDD + HIDD) // 4608

using bf16x8 = __attribute__((ext_vector_type(8))) short;
using f32x4  = __attribute__((ext_vector_type(4))) float;
using us4    = __attribute__((ext_vector_type(4))) unsigned short;

__device__ __forceinline__ unsigned short f2b(float f) {
    union { float f; uint32_t u; } v; v.f = f;
    uint32_t r = v.u + 0x7FFFu + ((v.u >> 16) & 1u);
    return (unsigned short)(r >> 16);
}

__device__ __forceinline__ us4 cvt4(f32x4 v) {
    us4 u;
    u[0] = f2b(v[0]); u[1] = f2b(v[1]); u[2] = f2b(v[2]); u[3] = f2b(v[3]);
    return u;
}

__device__ __forceinline__ float b2f_lo(uint32_t w) {
    union { uint32_t u; float f; } v; v.u = w << 16; return v.f;
}
__device__ __forceinline__ float b2f_hi(uint32_t w) {
    union { uint32_t u; float f; } v; v.u = w & 0xffff0000u; return v.f;
}

// ---------------------------------------------------------------------------
// Build X0 bf16 [8192][1280] = concat(box, emb[labels])
// ---------------------------------------------------------------------------
__global__ void k_build_x0(const float* __restrict__ box, const int* __restrict__ labels,
                           const float* __restrict__ emb, unsigned short* __restrict__ X0) {
    int n = blockIdx.x;
    int lab = labels[n];
    const f32x4* b = (const f32x4*)(box + (size_t)n * BOXD);
    const f32x4* e = (const f32x4*)(emb + (size_t)lab * EMBD);
    us4* o = (us4*)(X0 + (size_t)n * K0DIM);
    for (int j = threadIdx.x; j < K0DIM / 4; j += 256) {
        f32x4 v = (j < BOXD / 4) ? b[j] : e[j - BOXD / 4];
        o[j] = cvt4(v);
    }
}

// ---------------------------------------------------------------------------
// All 5 weight transposes in one dispatch (4096 blocks x 256 threads).
// fp32 src[K][No] -> bf16 dst[o][kOff + k] with row stride ld.
// ---------------------------------------------------------------------------
__global__ void k_transpose_all(const float* __restrict__ W_lin, const float* __restrict__ rel_W1,
                                const float* __restrict__ root_W1, const float* __restrict__ rel_W2,
                                const float* __restrict__ root_W2,
                                unsigned short* __restrict__ W0t, unsigned short* __restrict__ W1t,
                                unsigned short* __restrict__ W2t) {
    __shared__ float t[32][33];
    int bid = blockIdx.x;
    const float* src; unsigned short* dst; int No, ld, kOff, kb, ob;
    if (bid < 640)        { int g = bid;        src = W_lin;   dst = W0t; No = 512; ld = K0DIM; kOff = 0;    kb = g % 40;  ob = g / 40; }
    else if (bid < 2688)  { int g = bid - 640;  src = rel_W1;  dst = W1t; No = 512; ld = KSDIM; kOff = 0;    kb = g % 128; ob = g / 128; }
    else if (bid < 2944)  { int g = bid - 2688; src = root_W1; dst = W1t; No = 512; ld = KSDIM; kOff = 4096; kb = g % 16;  ob = g / 16; }
    else if (bid < 3968)  { int g = bid - 2944; src = rel_W2;  dst = W2t; No = 256; ld = KSDIM; kOff = 0;    kb = g % 128; ob = g / 128; }
    else                  { int g = bid - 3968; src = root_W2; dst = W2t; No = 256; ld = KSDIM; kOff = 4096; kb = g % 16;  ob = g / 16; }
    int kt = kb * 32, ot = ob * 32;
    int tx = threadIdx.x & 31, ty = threadIdx.x >> 5; // 32 x 8
#pragma unroll
    for (int i = 0; i < 4; i++) {
        int k = kt + ty + i * 8;
        t[ty + i * 8][tx] = src[(size_t)k * No + ot + tx];
    }
    __syncthreads();
#pragma unroll
    for (int i = 0; i < 4; i++) {
        int o = ot + ty + i * 8;
        dst[(size_t)o * ld + kOff + kt + tx] = f2b(t[tx][ty + i * 8]);
    }
}

// ---------------------------------------------------------------------------
// CSR build
// ---------------------------------------------------------------------------
__global__ void k_hist(const int* __restrict__ etype, const int* __restrict__ edst,
                       int* __restrict__ cnt) {
    int e = blockIdx.x * 256 + threadIdx.x;
    if (e >= NEDGES) return;
    atomicAdd(&cnt[etype[e] * NNODES + edst[e]], 1);
}

// 1024-thread two-level exclusive scan of cnt[65536] -> segstart[65537]
__global__ __launch_bounds__(1024) void k_scan(const int* __restrict__ cnt,
                                               int* __restrict__ segstart) {
    __shared__ int part[1024];
    __shared__ int sup[16];
    __shared__ int supx[16];
    int t = threadIdx.x;
    int base = t * 64;
    int s = 0;
    for (int i = 0; i < 64; i++) s += cnt[base + i];
    part[t] = s;
    __syncthreads();
    if (t < 16) {
        int a = 0;
        for (int i = 0; i < 64; i++) a += part[t * 64 + i];
        sup[t] = a;
    }
    __syncthreads();
    if (t == 0) {
        int a = 0;
        for (int i = 0; i < 16; i++) { supx[i] = a; a += sup[i]; }
    }
    __syncthreads();
    int a = supx[t >> 6];
    for (int i = (t & ~63); i < t; i++) a += part[i];
    for (int i = 0; i < 64; i++) { segstart[base + i] = a; a += cnt[base + i]; }
    if (t == 1023) segstart[NSEG] = a;
}

__global__ void k_scatter(const int* __restrict__ etype, const int* __restrict__ esrc,
                          const int* __restrict__ edst, const int* __restrict__ segstart,
                          int* __restrict__ cursor, int* __restrict__ esorted) {
    int e = blockIdx.x * 256 + threadIdx.x;
    if (e >= NEDGES) return;
    int key = etype[e] * NNODES + edst[e];
    int pos = atomicAdd(&cursor[key], 1);
    esorted[segstart[key] + pos] = esrc[e];
}

// ---------------------------------------------------------------------------
// Aggregation: one wave per (rel,dst) segment; bf16 x rows (16B/lane/edge),
// fp32 accumulate, 2-edge unroll; mean scale derived from segstart.
// ---------------------------------------------------------------------------
__global__ __launch_bounds__(256) void k_aggregate(
        const unsigned short* __restrict__ x, const int* __restrict__ segstart,
        const int* __restrict__ esorted, unsigned short* __restrict__ Xin) {
    int seg = blockIdx.x * 4 + (threadIdx.x >> 6);
    int lane = threadIdx.x & 63;
    int r = seg >> 13;          // /8192
    int dstn = seg & (NNODES - 1);
    float a[8] = {0, 0, 0, 0, 0, 0, 0, 0};
    float b[8] = {0, 0, 0, 0, 0, 0, 0, 0};
    int s0 = segstart[seg], s1 = segstart[seg + 1];
    int t = s0;
    for (; t + 2 <= s1; t += 2) {
        uint4 v0 = *(const uint4*)(x + (size_t)esorted[t] * HIDD + lane * 8);
        uint4 v1 = *(const uint4*)(x + (size_t)esorted[t + 1] * HIDD + lane * 8);
        a[0] += b2f_lo(v0.x); a[1] += b2f_hi(v0.x);
        a[2] += b2f_lo(v0.y); a[3] += b2f_hi(v0.y);
        a[4] += b2f_lo(v0.z); a[5] += b2f_hi(v0.z);
        a[6] += b2f_lo(v0.w); a[7] += b2f_hi(v0.w);
        b[0] += b2f_lo(v1.x); b[1] += b2f_hi(v1.x);
        b[2] += b2f_lo(v1.y); b[3] += b2f_hi(v1.y);
        b[4] += b2f_lo(v1.z); b[5] += b2f_hi(v1.z);
        b[6] += b2f_lo(v1.w); b[7] += b2f_hi(v1.w);
    }
    if (t < s1) {
        uint4 v0 = *(const uint4*)(x + (size_t)esorted[t] * HIDD + lane * 8);
        a[0] += b2f_lo(v0.x); a[1] += b2f_hi(v0.x);
        a[2] += b2f_lo(v0.y); a[3] += b2f_hi(v0.y);
        a[4] += b2f_lo(v0.z); a[5] += b2f_hi(v0.z);
        a[6] += b2f_lo(v0.w); a[7] += b2f_hi(v0.w);
    }
    float iv = (s1 > s0) ? (1.0f / (float)(s1 - s0)) : 1.0f;
#pragma unroll
    for (int j = 0; j < 8; j++) a[j] = (a[j] + b[j]) * iv;
    uint4 u;
    u.x = (uint32_t)f2b(a[0]) | ((uint32_t)f2b(a[1]) << 16);
    u.y = (uint32_t)f2b(a[2]) | ((uint32_t)f2b(a[3]) << 16);
    u.z = (uint32_t)f2b(a[4]) | ((uint32_t)f2b(a[5]) << 16);
    u.w = (uint32_t)f2b(a[6]) | ((uint32_t)f2b(a[7]) << 16);
    *(uint4*)(Xin + (size_t)dstn * KSDIM + r * HIDD + lane * 8) = u;
}

// ---------------------------------------------------------------------------
// bf16 MFMA GEMM, split-K partials. 128x128 tile, BK=64, 4 waves (2x2),
// acc[4][4] per wave (64x64 wave tile -> halved LDS-read redundancy).
// LDS [128][64]/buffer, XOR swizzle slot = chunk ^ (row&7), double-buffered,
// one vmcnt(0)+barrier drain per K-tile.
// ---------------------------------------------------------------------------
__global__ __launch_bounds__(256, 2) void k_gemm(
        const unsigned short* __restrict__ A,   // [M][K] bf16
        const unsigned short* __restrict__ Bt,  // [N][K] bf16
        float* __restrict__ P,                  // [S][M][N] partials
        int M, int N, int K, int Kc) {
    __shared__ unsigned short As[2][128 * 64];
    __shared__ unsigned short Bs[2][128 * 64];
    const int tid = threadIdx.x;
    const int lane = tid & 63, wid = tid >> 6;
    const int tiles_m = M >> 7;
    const int tm = blockIdx.x % tiles_m, tn = blockIdx.x / tiles_m;
    const int m0 = tm << 7, n0 = tn << 7;
    const int wr = wid >> 1, wc = wid & 1;       // 2 x 2 wave grid
    const int k0 = blockIdx.y * Kc;

    f32x4 acc[4][4];
#pragma unroll
    for (int i = 0; i < 4; i++)
#pragma unroll
        for (int j = 0; j < 4; j++) acc[i][j] = (f32x4){0.f, 0.f, 0.f, 0.f};

    // staging: instr i stages rows (tid>>3)+i*32, slot tid&7; source chunk
    // inverse-swizzled: LDS slot s of row r holds global chunk s^(r&7).
    const int rowg = tid >> 3;
    const int srcc = (tid & 7) ^ (rowg & 7);
    const unsigned short* gA = A  + (size_t)(m0 + rowg) * K + k0 + srcc * 8;
    const unsigned short* gB = Bt + (size_t)(n0 + rowg) * K + k0 + srcc * 8;
    const int ldsbase = wid * 512;  // elems; + i*2048 per instr; HW adds lane*16B

    auto stage = [&](int bsel, int kt) {
#pragma unroll
        for (int i = 0; i < 4; ++i) {
            __builtin_amdgcn_global_load_lds(
                (const __attribute__((address_space(1))) void*)(gA + kt + i * 32 * K),
                (__attribute__((address_space(3))) void*)&As[bsel][i * 2048 + ldsbase], 16, 0, 0);
            __builtin_amdgcn_global_load_lds(
                (const __attribute__((address_space(1))) void*)(gB + kt + i * 32 * K),
                (__attribute__((address_space(3))) void*)&Bs[bsel][i * 2048 + ldsbase], 16, 0, 0);
        }
    };

    const int arow = wr * 64 + (lane & 15);
    const int brow = wc * 64 + (lane & 15);
    const int l7 = lane & 7;
    const int c0 = lane >> 4;   // 0..3

    const int nt = Kc >> 6;
    int cur = 0;
    stage(0, 0);
    asm volatile("s_waitcnt vmcnt(0)" ::: "memory");
    __builtin_amdgcn_s_barrier();

    for (int t = 0; t < nt; ++t) {
        if (t + 1 < nt) stage(cur ^ 1, (t + 1) * 64);
#pragma unroll
        for (int s4 = 0; s4 < 2; ++s4) {
            const int slot = (c0 + s4 * 4) ^ l7;
            bf16x8 af[4], bfr[4];
#pragma unroll
            for (int m = 0; m < 4; m++)
                af[m] = *(const bf16x8*)&As[cur][(arow + m * 16) * 64 + slot * 8];
#pragma unroll
            for (int n = 0; n < 4; n++)
                bfr[n] = *(const bf16x8*)&Bs[cur][(brow + n * 16) * 64 + slot * 8];
#pragma unroll
            for (int m = 0; m < 4; m++)
#pragma unroll
                for (int n = 0; n < 4; n++)
                    acc[m][n] = __builtin_amdgcn_mfma_f32_16x16x32_bf16(af[m], bfr[n], acc[m][n], 0, 0, 0);
        }
        if (t + 1 < nt) {
            asm volatile("s_waitcnt vmcnt(0)" ::: "memory");
            __builtin_amdgcn_s_barrier();
            cur ^= 1;
        }
    }

    float* Pout = P + (size_t)blockIdx.y * M * N;
    const int crow0 = m0 + wr * 64 + (lane >> 4) * 4;
    const int ccol0 = n0 + wc * 64 + (lane & 15);
#pragma unroll
    for (int n = 0; n < 4; n++) {
        int col = ccol0 + n * 16;
#pragma unroll
        for (int m = 0; m < 4; m++)
#pragma unroll
            for (int r = 0; r < 4; r++)
                Pout[(size_t)(crow0 + m * 16 + r) * N + col] = acc[m][n][r];
    }
}

// ---------------------------------------------------------------------------
// Reduce S=2 partials + bias (+ReLU) -> bf16 x AND Xin root columns (N=512)
// ---------------------------------------------------------------------------
template <int RELU>
__global__ void k_reduce_bf(const float* __restrict__ P, const float* __restrict__ bias,
                            unsigned short* __restrict__ xbf, unsigned short* __restrict__ Xin,
                            int MN) {
    int idx = (blockIdx.x * 256 + threadIdx.x) * 4;
    f32x4 v = *(const f32x4*)&P[idx];
    v += *(const f32x4*)&P[(size_t)MN + idx];
    v += *(const f32x4*)&bias[idx & 511];
    if (RELU) {
#pragma unroll
        for (int j = 0; j < 4; j++) v[j] = fmaxf(v[j], 0.f);
    }
    us4 u = cvt4(v);
    *(us4*)&xbf[idx] = u;
    int row = idx >> 9, col = idx & 511;
    *(us4*)&Xin[(size_t)row * KSDIM + NRELS * HIDD + col] = u;
}

// Reduce S=4 partials + bias -> fp32 out (layer 2; out may alias P[0])
__global__ void k_reduce4(const float* P, const float* __restrict__ bias,
                          float* out, int MN, int N) {
    int idx = (blockIdx.x * 256 + threadIdx.x) * 4;
    f32x4 v = *(const f32x4*)&P[idx];
#pragma unroll
    for (int s = 1; s < 4; s++) v += *(const f32x4*)&P[(size_t)s * MN + idx];
    v += *(const f32x4*)&bias[idx & (N - 1)];
    *(f32x4*)&out[idx] = v;
}

// ---------------------------------------------------------------------------
// Fused pool (mean over 128 nodes) + classifier + softmax. 64 blocks.
// ---------------------------------------------------------------------------
__global__ void k_poolclass(const float* __restrict__ x3, const float* __restrict__ Wc1,
                            const float* __restrict__ bc1, const float* __restrict__ Wc2,
                            const float* __restrict__ bc2, float* __restrict__ out) {
    __shared__ float p[256];
    __shared__ float h[256];
    __shared__ float lg[2];
    int b = blockIdx.x, o = threadIdx.x;
    float s = 0.f;
    for (int i = 0; i < 128; i++) s += x3[(size_t)(b * 128 + i) * OUTD + o];
    p[o] = s * (1.0f / 128.0f);
    __syncthreads();
    float s1 = bc1[o];
    for (int i = 0; i < 256; i++) s1 += p[i] * Wc1[i * 256 + o];
    h[o] = s1;
    __syncthreads();
    if (o < 2) {
        float t = bc2[o];
        for (int i = 0; i < 256; i++) t += h[i] * Wc2[i * 2 + o];
        lg[o] = t;
        out[b * 2 + o] = t;
    }
    __syncthreads();
    if (o == 0) {
        float m = fmaxf(lg[0], lg[1]);
        float e0 = expf(lg[0] - m), e1 = expf(lg[1] - m);
        float inv = 1.0f / (e0 + e1);
        out[128 + b * 2 + 0] = e0 * inv;
        out[128 + b * 2 + 1] = e1 * inv;
    }
}

// ---------------------------------------------------------------------------
extern "C" void kernel_launch(void* const* d_in, const int* in_sizes, int n_in,
                              void* d_out, int out_size, void* d_ws, size_t ws_size,
                              hipStream_t stream) {
    const float* box     = (const float*)d_in[0];
    const int*   labels  = (const int*)d_in[1];
    const int*   eidx    = (const int*)d_in[2];
    const int*   etype   = (const int*)d_in[3];
    const float* emb     = (const float*)d_in[5];
    const float* W_lin   = (const float*)d_in[6];
    const float* b_lin   = (const float*)d_in[7];
    const float* rel_W1  = (const float*)d_in[8];
    const float* root_W1 = (const float*)d_in[9];
    const float* b1      = (const float*)d_in[10];
    const float* rel_W2  = (const float*)d_in[11];
    const float* root_W2 = (const float*)d_in[12];
    const float* b2      = (const float*)d_in[13];
    const float* Wc1     = (const float*)d_in[14];
    const float* bc1     = (const float*)d_in[15];
    const float* Wc2     = (const float*)d_in[16];
    const float* bc2     = (const float*)d_in[17];
    const int* esrc = eidx;
    const int* edst = eidx + NEDGES;

    char* ws = (char*)d_ws;
    size_t off = 0;
    auto alloc = [&](size_t bytes) -> char* {
        char* p = ws + off;
        off += (bytes + 255) & ~(size_t)255;
        return p;
    };
    // Split-K partial region (33.5 MB; S=4 layer-2 exactly fits since 4*256==2*512).
    // x3 aliases it (elementwise reduce, safe).
    float* Pp = (float*)alloc((size_t)2 * NNODES * HIDD * 4);
    float* x3 = Pp;
    unsigned short* X0   = (unsigned short*)alloc((size_t)NNODES * K0DIM * 2);
    // xbf (bf16 x1/x2, 8 MB) aliases X0 (20 MB): X0 dead after layer-0 GEMM.
    unsigned short* xbf  = X0;
    unsigned short* W0t  = (unsigned short*)alloc((size_t)HIDD * K0DIM * 2);
    unsigned short* W1t  = (unsigned short*)alloc((size_t)HIDD * KSDIM * 2);
    unsigned short* W2t  = (unsigned short*)alloc((size_t)OUTD * KSDIM * 2);
    unsigned short* Xin  = (unsigned short*)alloc((size_t)NNODES * KSDIM * 2);
    int*   cnt     = (int*)alloc((size_t)NSEG * 4);
    int*   cursor  = (int*)alloc((size_t)NSEG * 4);   // contiguous with cnt
    int*   segst   = (int*)alloc((size_t)(NSEG + 1) * 4);
    int*   esorted = (int*)alloc((size_t)NEDGES * 4);
    if (off > ws_size) return;

    float* out = (float*)d_out;

    // --- CSR + weight prep ---
    hipMemsetAsync(cnt, 0, (size_t)2 * NSEG * 4, stream);   // cnt + cursor
    k_build_x0<<<NNODES, 256, 0, stream>>>(box, labels, emb, X0);
    k_transpose_all<<<4096, 256, 0, stream>>>(W_lin, rel_W1, root_W1, rel_W2, root_W2,
                                              W0t, W1t, W2t);
    k_hist<<<NEDGES / 256, 256, 0, stream>>>(etype, edst, cnt);
    k_scan<<<1, 1024, 0, stream>>>(cnt, segst);
    k_scatter<<<NEDGES / 256, 256, 0, stream>>>(etype, esrc, edst, segst, cursor, esorted);

    // --- layer 0: x1 = X0 @ W_lin + b_lin  (S=2, Kc=640) ---
    k_gemm<<<dim3((NNODES / 128) * (HIDD / 128), 2), 256, 0, stream>>>(
        X0, W0t, Pp, NNODES, HIDD, K0DIM, K0DIM / 2);
    k_reduce_bf<0><<<(NNODES * HIDD) / 1024, 256, 0, stream>>>(
        Pp, b_lin, xbf, Xin, NNODES * HIDD);

    // --- RGCN layer 1 (S=2, Kc=2304) ---
    k_aggregate<<<NSEG / 4, 256, 0, stream>>>(xbf, segst, esorted, Xin);
    k_gemm<<<dim3((NNODES / 128) * (HIDD / 128), 2), 256, 0, stream>>>(
        Xin, W1t, Pp, NNODES, HIDD, KSDIM, KSDIM / 2);
    k_reduce_bf<1><<<(NNODES * HIDD) / 1024, 256, 0, stream>>>(
        Pp, b1, xbf, Xin, NNODES * HIDD);

    // --- RGCN layer 2 (S=4, Kc=1152) ---
    k_aggregate<<<NSEG / 4, 256, 0, stream>>>(xbf, segst, esorted, Xin);
    k_gemm<<<dim3((NNODES / 128) * (OUTD / 128), 4), 256, 0, stream>>>(
        Xin, W2t, Pp, NNODES, OUTD, KSDIM, KSDIM / 4);
    k_reduce4<<<(NNODES * OUTD) / 1024, 256, 0, stream>>>(
        Pp, b2, x3, NNODES * OUTD, OUTD);

    // --- fused pooling + classifier ---
    k_poolclass<<<64, 256, 0, stream>>>(x3, Wc1, bc1, Wc2, bc2, out);
}